// Round 5
// baseline (273.436 us; speedup 1.0000x reference)
//
#include <hip/hip_runtime.h>
#include <hip/hip_bf16.h>
#include <math.h>

#define SEQ 4096
#define HID 1024
#define DH  64
#define NB  8
#define QSCALE 0.18033688011112042f   // 0.125 * log2(e): folds softmax scale + exp->exp2

typedef unsigned short ushort_t;
typedef unsigned int   uint_t;
typedef __attribute__((ext_vector_type(8))) short  bf16x8;
typedef __attribute__((ext_vector_type(4))) float  f32x4;
typedef __attribute__((ext_vector_type(4))) uint_t u32x4;
typedef __attribute__((ext_vector_type(2))) uint_t u32x2;

static __device__ __forceinline__ ushort_t f2bf(float f) {
    __hip_bfloat16 h = __float2bfloat16(f);   // RNE
    return *reinterpret_cast<ushort_t*>(&h);
}
// fast round-to-nearest bf16 (no NaN path; inputs finite >= 0)
static __device__ __forceinline__ ushort_t f2bf_fast(float f) {
    uint_t u = __float_as_uint(f);
    return (ushort_t)((u + 0x8000u) >> 16);
}
static __device__ __forceinline__ uint_t bfpair(float lo, float hi) {
    return (uint_t)f2bf_fast(lo) | ((uint_t)f2bf_fast(hi) << 16);
}

// async global->LDS DMA, 16 B per lane; lds dest = wave-uniform base + lane*16
static __device__ __forceinline__ void gld_lds16(const void* g, void* s) {
    __builtin_amdgcn_global_load_lds(
        (const __attribute__((address_space(1))) void*)g,
        (__attribute__((address_space(3))) void*)s, 16, 0, 0);
}

// ---------------------------------------------------------------------------
// Kernel 0: build wts = [Wq*QSCALE | Wk | Wv] transposed to [col][k], bf16,
// pre-swizzled per 64-k tile so proj can stage it as a flat copy.
// ---------------------------------------------------------------------------
__global__ __launch_bounds__(256) void prep_w(
    const float* __restrict__ Wq, const float* __restrict__ Wk,
    const float* __restrict__ Wv, ushort_t* __restrict__ wts)
{
    __shared__ ushort_t tr[64][72];   // [k][c] bf16
    const int bx   = blockIdx.x;      // 48 = 3 mats x 16 k-tiles
    const int mmat = bx >> 4;
    const int kt   = bx & 15;
    const float* W  = (mmat == 0) ? Wq : (mmat == 1) ? Wk : Wv;
    const float  sc = (mmat == 0) ? QSCALE : 1.0f;

    const int t  = threadIdx.x;
    const int kr = t >> 2, kc = (t & 3) * 16;
    const float* src = W + (size_t)(kt * 64 + kr) * DH + kc;
    float4 a0 = *(const float4*)(src);
    float4 a1 = *(const float4*)(src + 4);
    float4 a2 = *(const float4*)(src + 8);
    float4 a3 = *(const float4*)(src + 12);
    float vv[16] = {a0.x,a0.y,a0.z,a0.w, a1.x,a1.y,a1.z,a1.w,
                    a2.x,a2.y,a2.z,a2.w, a3.x,a3.y,a3.z,a3.w};
    #pragma unroll
    for (int i = 0; i < 16; ++i) tr[kr][kc + i] = f2bf(vv[i] * sc);
    __syncthreads();

    const int cl = t >> 2, jc = (t & 3) * 16;
    const int c  = mmat * 64 + cl;
    ushort_t* dst = wts + kt * 12288 + c * 64;
    #pragma unroll
    for (int jj = 0; jj < 16; ++jj) {
        int j = jc + jj;
        dst[((j >> 3) ^ (cl & 7)) * 8 + (j & 7)] = tr[j][cl];
    }
}

// ---------------------------------------------------------------------------
// Kernel 1: fused QKV projection, bf16 MFMA, double-buffered (1 barrier/iter).
// Outputs: qimg natural [s][d] bf16 (Q pre-scaled by QSCALE);
//          kimg/vimg as pre-swizzled per-64-row tile images (= attn LDS image).
// ---------------------------------------------------------------------------
__global__ __launch_bounds__(256) void qkv_proj(
    const float* __restrict__ x, const ushort_t* __restrict__ wts,
    const float* __restrict__ bq, const float* __restrict__ bk,
    const float* __restrict__ bv,
    ushort_t* __restrict__ qimg, ushort_t* __restrict__ kimg,
    ushort_t* __restrict__ vimg)
{
    __shared__ ushort_t xs[2][64][72];
    __shared__ ushort_t bw[2][12288];

    const int t  = threadIdx.x;
    const int w  = t >> 6, l = t & 63, lr = l & 15, lg = l >> 4;
    const int row0 = blockIdx.x * 64;
    const int sxr = t >> 2, sxc = (t & 3) * 16;
    const int ch0 = (lg ^ (lr & 7)) * 8;
    const int ch1 = ((lg + 4) ^ (lr & 7)) * 8;

    f32x4 acc[4][3];
    #pragma unroll
    for (int i = 0; i < 4; ++i)
        #pragma unroll
        for (int j = 0; j < 3; ++j) acc[i][j] = (f32x4){0.f,0.f,0.f,0.f};

    float4 Xf[4];
    u32x4  Bf[6];
    {   // prologue: tile 0 loads
        const float* xr = x + (size_t)(row0 + sxr) * HID + sxc;
        Xf[0] = *(const float4*)(xr);      Xf[1] = *(const float4*)(xr + 4);
        Xf[2] = *(const float4*)(xr + 8);  Xf[3] = *(const float4*)(xr + 12);
        const char* bsrc = (const char*)wts + t * 16;
        #pragma unroll
        for (int i = 0; i < 6; ++i) Bf[i] = *(const u32x4*)(bsrc + i * 4096);
    }

    for (int kt = 0; kt < 16; ++kt) {
        const int buf = kt & 1;
        // A: write staged regs -> LDS buf
        {
            u32x4 p0, p1;
            p0.x = bfpair(Xf[0].x, Xf[0].y);
            p0.y = bfpair(Xf[0].z, Xf[0].w);
            p0.z = bfpair(Xf[1].x, Xf[1].y);
            p0.w = bfpair(Xf[1].z, Xf[1].w);
            p1.x = bfpair(Xf[2].x, Xf[2].y);
            p1.y = bfpair(Xf[2].z, Xf[2].w);
            p1.z = bfpair(Xf[3].x, Xf[3].y);
            p1.w = bfpair(Xf[3].z, Xf[3].w);
            *(u32x4*)&xs[buf][sxr][sxc]     = p0;
            *(u32x4*)&xs[buf][sxr][sxc + 8] = p1;
            char* bdst = (char*)&bw[buf][0] + t * 16;
            #pragma unroll
            for (int i = 0; i < 6; ++i) *(u32x4*)(bdst + i * 4096) = Bf[i];
        }
        __syncthreads();
        // C: prefetch tile kt+1 (in flight across compute)
        if (kt < 15) {
            const float* xr = x + (size_t)(row0 + sxr) * HID + (kt + 1) * 64 + sxc;
            Xf[0] = *(const float4*)(xr);      Xf[1] = *(const float4*)(xr + 4);
            Xf[2] = *(const float4*)(xr + 8);  Xf[3] = *(const float4*)(xr + 12);
            const char* bsrc = (const char*)wts + (kt + 1) * 24576 + t * 16;
            #pragma unroll
            for (int i = 0; i < 6; ++i) Bf[i] = *(const u32x4*)(bsrc + i * 4096);
        }
        // D: compute tile kt
        bf16x8 af0[4], af1[4];
        #pragma unroll
        for (int rt = 0; rt < 4; ++rt) {
            af0[rt] = *(bf16x8*)&xs[buf][rt * 16 + lr][lg * 8];
            af1[rt] = *(bf16x8*)&xs[buf][rt * 16 + lr][lg * 8 + 32];
        }
        #pragma unroll
        for (int ctl = 0; ctl < 3; ++ctl) {
            const int c = (w * 3 + ctl) * 16 + lr;
            bf16x8 b0 = *(bf16x8*)&bw[buf][c * 64 + ch0];
            bf16x8 b1 = *(bf16x8*)&bw[buf][c * 64 + ch1];
            #pragma unroll
            for (int rt = 0; rt < 4; ++rt) {
                acc[rt][ctl] = __builtin_amdgcn_mfma_f32_16x16x32_bf16(
                    af0[rt], b0, acc[rt][ctl], 0, 0, 0);
                acc[rt][ctl] = __builtin_amdgcn_mfma_f32_16x16x32_bf16(
                    af1[rt], b1, acc[rt][ctl], 0, 0, 0);
            }
        }
    }

    // epilogue: +bias, cast, scatter to layout images
    #pragma unroll
    for (int ctl = 0; ctl < 3; ++ctl) {
        const int c    = (w * 3 + ctl) * 16 + lr;
        const int mmat = c >> 6;
        const int cc   = c & 63;
        const float* bp = (mmat == 0) ? bq : (mmat == 1) ? bk : bv;
        const float bias = bp[cc] * (mmat == 0 ? QSCALE : 1.0f);
        #pragma unroll
        for (int rt = 0; rt < 4; ++rt)
            #pragma unroll
            for (int r = 0; r < 4; ++r) {
                const int s = row0 + rt * 16 + lg * 4 + r;
                const ushort_t v = f2bf(acc[rt][ctl][r] + bias);
                if (mmat == 0)
                    qimg[(size_t)s * 64 + cc] = v;
                else if (mmat == 1)
                    kimg[(size_t)(s >> 6) * 4096 + (s & 63) * 64 +
                         ((cc >> 3) ^ (s & 7)) * 8 + (cc & 7)] = v;
                else
                    vimg[(size_t)(s >> 6) * 4096 + (size_t)cc * 64 +
                         (((s & 63) >> 3) ^ (cc & 7)) * 8 + (s & 7)] = v;
            }
    }
}

// ---------------------------------------------------------------------------
// Kernel 2: causal flash attention, bf16 MFMA, S^T formulation.
// S^T = mfma(K, Q): each lane holds 16 scores for ONE q-row with
// reg-consecutive kv -> P written as 4x ds_write_b64, l = in-lane sum
// (no ones-MFMAs, no shuffles in-loop). PV: O^T = mfma(V^T, P^T).
// Double-buffered DMA staging (41.98 KB LDS -> 3 blocks/CU).
// Pairwise-balanced qt map: co-resident (bx, bx+256) sum to 65 tile-iters.
// ---------------------------------------------------------------------------
__global__ __launch_bounds__(256) void attn(
    const ushort_t* __restrict__ qimg, const ushort_t* __restrict__ kimg,
    const ushort_t* __restrict__ vimg, float* __restrict__ outg)
{
    __shared__ ushort_t kvs[2][8192];   // slot: K img bytes 0..8191, V img 8192..16383
    __shared__ ushort_t ps[64][72];     // P[q][kv]; wave w owns rows 16w..16w+15

    const int t  = threadIdx.x;
    const int w  = t >> 6, l = t & 63, lr = l & 15, g = l >> 4;
    const int bx = blockIdx.x;
    const int qt = (bx < 256) ? (63 - (bx >> 3)) : ((bx - 256) >> 3);
    const int b  = bx & 7;
    const int q0 = qt * 64;
    const int ch0 = (g ^ (lr & 7)) * 8;
    const int ch1 = ((g + 4) ^ (lr & 7)) * 8;
    const int qq  = q0 + w * 16 + lr;          // this lane's q-row (global)

    // Q as B-fragments (n = q = lr, k = d = g*8+j)
    bf16x8 qf0, qf1;
    {
        const ushort_t* qp = qimg + (size_t)(b * SEQ + qq) * 64 + g * 8;
        qf0 = *(const bf16x8*)(qp);
        qf1 = *(const bf16x8*)(qp + 32);
    }

    f32x4 o[4];
    #pragma unroll
    for (int dt = 0; dt < 4; ++dt) o[dt] = (f32x4){0.f,0.f,0.f,0.f};
    float lpart = 0.f;

    const char* kbase = (const char*)kimg + (size_t)b * 524288;
    const char* vbase = (const char*)vimg + (size_t)b * 524288;
    const int wo = w * 1024;
    const int lo = l * 16;

    // prologue: stage tile 0 -> slot 0
    {
        char* lk = (char*)&kvs[0][0];
        gld_lds16(kbase + wo + lo,        lk + wo);
        gld_lds16(kbase + wo + lo + 4096, lk + wo + 4096);
        gld_lds16(vbase + wo + lo,        lk + wo + 8192);
        gld_lds16(vbase + wo + lo + 4096, lk + wo + 12288);
    }

    for (int kt = 0; kt <= qt; ++kt) {
        const int cur = kt & 1;
        __syncthreads();                      // drains DMA for tile kt
        if (kt < qt) {                        // stage tile kt+1 into other slot
            const char* ks = kbase + (size_t)(kt + 1) * 8192;
            const char* vs = vbase + (size_t)(kt + 1) * 8192;
            char*       lk = (char*)&kvs[cur ^ 1][0];
            gld_lds16(ks + wo + lo,        lk + wo);
            gld_lds16(ks + wo + lo + 4096, lk + wo + 4096);
            gld_lds16(vs + wo + lo,        lk + wo + 8192);
            gld_lds16(vs + wo + lo + 4096, lk + wo + 12288);
        }

        // S^T = K . Q^T : A = K rows (m = kv), B = Q (n = q)
        const ushort_t* kb = &kvs[cur][0];
        f32x4 s[4];
        #pragma unroll
        for (int ct = 0; ct < 4; ++ct) {
            const int rowb = (ct * 16 + lr) * 64;
            bf16x8 kf0 = *(const bf16x8*)(kb + rowb + ch0);
            bf16x8 kf1 = *(const bf16x8*)(kb + rowb + ch1);
            s[ct] = (f32x4){0.f,0.f,0.f,0.f};
            s[ct] = __builtin_amdgcn_mfma_f32_16x16x32_bf16(kf0, qf0, s[ct], 0, 0, 0);
            s[ct] = __builtin_amdgcn_mfma_f32_16x16x32_bf16(kf1, qf1, s[ct], 0, 0, 0);
        }

        // exp2 + pack + P-write (lane's kv = k0 + ct*16 + g*4 + r, q = qq)
        if (kt == qt) {          // diagonal: causal mask
            const int kvb = kt * 64 + g * 4;
            #pragma unroll
            for (int ct = 0; ct < 4; ++ct) {
                float p0 = ((kvb + ct*16 + 0) > qq) ? 0.f : __builtin_amdgcn_exp2f(s[ct][0]);
                float p1 = ((kvb + ct*16 + 1) > qq) ? 0.f : __builtin_amdgcn_exp2f(s[ct][1]);
                float p2 = ((kvb + ct*16 + 2) > qq) ? 0.f : __builtin_amdgcn_exp2f(s[ct][2]);
                float p3 = ((kvb + ct*16 + 3) > qq) ? 0.f : __builtin_amdgcn_exp2f(s[ct][3]);
                lpart += (p0 + p1) + (p2 + p3);
                u32x2 pk = { bfpair(p0, p1), bfpair(p2, p3) };
                *(u32x2*)&ps[w * 16 + lr][ct * 16 + g * 4] = pk;
            }
        } else {
            #pragma unroll
            for (int ct = 0; ct < 4; ++ct) {
                float p0 = __builtin_amdgcn_exp2f(s[ct][0]);
                float p1 = __builtin_amdgcn_exp2f(s[ct][1]);
                float p2 = __builtin_amdgcn_exp2f(s[ct][2]);
                float p3 = __builtin_amdgcn_exp2f(s[ct][3]);
                lpart += (p0 + p1) + (p2 + p3);
                u32x2 pk = { bfpair(p0, p1), bfpair(p2, p3) };
                *(u32x2*)&ps[w * 16 + lr][ct * 16 + g * 4] = pk;
            }
        }
        // cross-lane (within-wave) LDS dependence: drain DS queue
        asm volatile("s_waitcnt lgkmcnt(0)" ::: "memory");

        // O^T += V^T . P^T : A = V^T rows (m = d), B = P^T (n = q, k = kv)
        bf16x8 pf0 = *(const bf16x8*)&ps[w * 16 + lr][g * 8];
        bf16x8 pf1 = *(const bf16x8*)&ps[w * 16 + lr][32 + g * 8];
        const ushort_t* vb = &kvs[cur][4096];
        #pragma unroll
        for (int dt = 0; dt < 4; ++dt) {
            const int rowb = (dt * 16 + lr) * 64;
            bf16x8 vf0 = *(const bf16x8*)(vb + rowb + ch0);
            bf16x8 vf1 = *(const bf16x8*)(vb + rowb + ch1);
            o[dt] = __builtin_amdgcn_mfma_f32_16x16x32_bf16(vf0, pf0, o[dt], 0, 0, 0);
            o[dt] = __builtin_amdgcn_mfma_f32_16x16x32_bf16(vf1, pf1, o[dt], 0, 0, 0);
        }
    }

    // reduce l across the 4 quads (same q lives in lanes differing in bits 4,5)
    lpart += __shfl_xor(lpart, 16);
    lpart += __shfl_xor(lpart, 32);
    const float inv = 1.0f / lpart;

    // store: lane owns q-row qq; o[dt] regs are d = dt*16 + g*4 + r
    float* orow = outg + (size_t)(b * SEQ + qq) * 64;
    #pragma unroll
    for (int dt = 0; dt < 4; ++dt) {
        float4 val = { o[dt][0] * inv, o[dt][1] * inv,
                       o[dt][2] * inv, o[dt][3] * inv };
        *(float4*)&orow[dt * 16 + g * 4] = val;
    }
}

extern "C" void kernel_launch(void* const* d_in, const int* in_sizes, int n_in,
                              void* d_out, int out_size, void* d_ws, size_t ws_size,
                              hipStream_t stream) {
    const float* x  = (const float*)d_in[0];
    const float* Wq = (const float*)d_in[1];
    const float* bq = (const float*)d_in[2];
    const float* Wk = (const float*)d_in[3];
    const float* bk = (const float*)d_in[4];
    const float* Wv = (const float*)d_in[5];
    const float* bv = (const float*)d_in[6];
    float* out = (float*)d_out;

    const size_t per = (size_t)NB * SEQ * DH;   // 2,097,152 bf16 elems = 4 MB
    ushort_t* q   = (ushort_t*)d_ws;
    ushort_t* k   = q + per;
    ushort_t* v   = k + per;
    ushort_t* wts = v + per;                    // 196,608 bf16 = 384 KB

    prep_w  <<<dim3(48),  256, 0, stream>>>(Wq, Wk, Wv, wts);
    qkv_proj<<<dim3(512), 256, 0, stream>>>(x, wts, bq, bk, bv, q, k, v);
    attn    <<<dim3(512), 256, 0, stream>>>(q, k, v, out);
}

// Round 6
// 259.011 us; speedup vs baseline: 1.0557x; 1.0557x over previous
//
#include <hip/hip_runtime.h>
#include <hip/hip_bf16.h>
#include <math.h>

#define SEQ 4096
#define HID 1024
#define DH  64
#define NB  8
#define QSCALE 0.18033688011112042f   // 0.125 * log2(e): folds softmax scale + exp->exp2

typedef unsigned short ushort_t;
typedef unsigned int   uint_t;
typedef __attribute__((ext_vector_type(8))) short  bf16x8;
typedef __attribute__((ext_vector_type(4))) float  f32x4;
typedef __attribute__((ext_vector_type(4))) uint_t u32x4;
typedef __attribute__((ext_vector_type(2))) uint_t u32x2;

static __device__ __forceinline__ ushort_t f2bf(float f) {
    __hip_bfloat16 h = __float2bfloat16(f);   // RNE
    return *reinterpret_cast<ushort_t*>(&h);
}
// fast round-to-nearest bf16 (no NaN path; inputs finite)
static __device__ __forceinline__ ushort_t f2bf_fast(float f) {
    uint_t u = __float_as_uint(f);
    return (ushort_t)((u + 0x8000u) >> 16);
}
static __device__ __forceinline__ uint_t bfpair(float lo, float hi) {
    return (uint_t)f2bf_fast(lo) | ((uint_t)f2bf_fast(hi) << 16);
}

// async global->LDS DMA, 16 B per lane; lds dest = wave-uniform base + lane*16
static __device__ __forceinline__ void gld_lds16(const void* g, void* s) {
    __builtin_amdgcn_global_load_lds(
        (const __attribute__((address_space(1))) void*)g,
        (__attribute__((address_space(3))) void*)s, 16, 0, 0);
}

// ---------------------------------------------------------------------------
// Kernel 0: build wts = [Wq*QSCALE | Wk | Wv] transposed to [col][k], bf16,
// pre-swizzled per 64-k tile so proj can stage it as a flat copy/DMA.
// ---------------------------------------------------------------------------
__global__ __launch_bounds__(256) void prep_w(
    const float* __restrict__ Wq, const float* __restrict__ Wk,
    const float* __restrict__ Wv, ushort_t* __restrict__ wts)
{
    __shared__ ushort_t tr[64][72];   // [k][c] bf16
    const int bx   = blockIdx.x;      // 48 = 3 mats x 16 k-tiles
    const int mmat = bx >> 4;
    const int kt   = bx & 15;
    const float* W  = (mmat == 0) ? Wq : (mmat == 1) ? Wk : Wv;
    const float  sc = (mmat == 0) ? QSCALE : 1.0f;

    const int t  = threadIdx.x;
    const int kr = t >> 2, kc = (t & 3) * 16;
    const float* src = W + (size_t)(kt * 64 + kr) * DH + kc;
    float4 a0 = *(const float4*)(src);
    float4 a1 = *(const float4*)(src + 4);
    float4 a2 = *(const float4*)(src + 8);
    float4 a3 = *(const float4*)(src + 12);
    float vv[16] = {a0.x,a0.y,a0.z,a0.w, a1.x,a1.y,a1.z,a1.w,
                    a2.x,a2.y,a2.z,a2.w, a3.x,a3.y,a3.z,a3.w};
    #pragma unroll
    for (int i = 0; i < 16; ++i) tr[kr][kc + i] = f2bf(vv[i] * sc);
    __syncthreads();

    const int cl = t >> 2, jc = (t & 3) * 16;
    const int c  = mmat * 64 + cl;
    ushort_t* dst = wts + kt * 12288 + c * 64;
    #pragma unroll
    for (int jj = 0; jj < 16; ++jj) {
        int j = jc + jj;
        dst[((j >> 3) ^ (cl & 7)) * 8 + (j & 7)] = tr[j][cl];
    }
}

// ---------------------------------------------------------------------------
// Kernel 1: fused QKV projection, bf16 MFMA, double-buffered, 1 barrier/iter.
// W staged via global_load_lds DMA (wts already in LDS-image layout);
// x staged through regs (fp32 -> bf16 cvt needed).
// ---------------------------------------------------------------------------
__global__ __launch_bounds__(256) void qkv_proj(
    const float* __restrict__ x, const ushort_t* __restrict__ wts,
    const float* __restrict__ bq, const float* __restrict__ bk,
    const float* __restrict__ bv,
    ushort_t* __restrict__ qimg, ushort_t* __restrict__ kimg,
    ushort_t* __restrict__ vimg)
{
    __shared__ ushort_t xs[2][64][72];
    __shared__ ushort_t bw[2][12288];

    const int t  = threadIdx.x;
    const int w  = t >> 6, l = t & 63, lr = l & 15, lg = l >> 4;
    const int row0 = blockIdx.x * 64;
    const int sxr = t >> 2, sxc = (t & 3) * 16;
    const int ch0 = (lg ^ (lr & 7)) * 8;
    const int ch1 = ((lg + 4) ^ (lr & 7)) * 8;

    f32x4 acc[4][3];
    #pragma unroll
    for (int i = 0; i < 4; ++i)
        #pragma unroll
        for (int j = 0; j < 3; ++j) acc[i][j] = (f32x4){0.f,0.f,0.f,0.f};

    const char* wbase = (const char*)wts;   // per-lane src offset below
    const int   wlo   = w * 1024 + l * 16;  // lane's flat byte offset in a 24 KB slice

    float4 Xf[4];
    {   // prologue: x tile 0 regs + DMA wts tile 0 -> bw[0]
        const float* xr = x + (size_t)(row0 + sxr) * HID + sxc;
        Xf[0] = *(const float4*)(xr);      Xf[1] = *(const float4*)(xr + 4);
        Xf[2] = *(const float4*)(xr + 8);  Xf[3] = *(const float4*)(xr + 12);
        char* bdst = (char*)&bw[0][0] + w * 1024;
        #pragma unroll
        for (int i = 0; i < 6; ++i)
            gld_lds16(wbase + wlo + i * 4096, bdst + i * 4096);
    }

    for (int kt = 0; kt < 16; ++kt) {
        const int buf = kt & 1;
        // A: write staged x regs -> LDS buf
        {
            u32x4 p0, p1;
            p0.x = bfpair(Xf[0].x, Xf[0].y);
            p0.y = bfpair(Xf[0].z, Xf[0].w);
            p0.z = bfpair(Xf[1].x, Xf[1].y);
            p0.w = bfpair(Xf[1].z, Xf[1].w);
            p1.x = bfpair(Xf[2].x, Xf[2].y);
            p1.y = bfpair(Xf[2].z, Xf[2].w);
            p1.z = bfpair(Xf[3].x, Xf[3].y);
            p1.w = bfpair(Xf[3].z, Xf[3].w);
            *(u32x4*)&xs[buf][sxr][sxc]     = p0;
            *(u32x4*)&xs[buf][sxr][sxc + 8] = p1;
        }
        __syncthreads();   // drains xs writes (lgkm) + bw[buf] DMA (vm)
        // C: prefetch tile kt+1 (x -> regs, wts -> DMA into other buffer)
        if (kt < 15) {
            const float* xr = x + (size_t)(row0 + sxr) * HID + (kt + 1) * 64 + sxc;
            Xf[0] = *(const float4*)(xr);      Xf[1] = *(const float4*)(xr + 4);
            Xf[2] = *(const float4*)(xr + 8);  Xf[3] = *(const float4*)(xr + 12);
            char* bdst = (char*)&bw[buf ^ 1][0] + w * 1024;
            const char* bsrc = wbase + (size_t)(kt + 1) * 24576 + wlo;
            #pragma unroll
            for (int i = 0; i < 6; ++i)
                gld_lds16(bsrc + i * 4096, bdst + i * 4096);
        }
        // D: compute tile kt
        bf16x8 af0[4], af1[4];
        #pragma unroll
        for (int rt = 0; rt < 4; ++rt) {
            af0[rt] = *(bf16x8*)&xs[buf][rt * 16 + lr][lg * 8];
            af1[rt] = *(bf16x8*)&xs[buf][rt * 16 + lr][lg * 8 + 32];
        }
        #pragma unroll
        for (int ctl = 0; ctl < 3; ++ctl) {
            const int c = (w * 3 + ctl) * 16 + lr;
            bf16x8 b0 = *(bf16x8*)&bw[buf][c * 64 + ch0];
            bf16x8 b1 = *(bf16x8*)&bw[buf][c * 64 + ch1];
            #pragma unroll
            for (int rt = 0; rt < 4; ++rt) {
                acc[rt][ctl] = __builtin_amdgcn_mfma_f32_16x16x32_bf16(
                    af0[rt], b0, acc[rt][ctl], 0, 0, 0);
                acc[rt][ctl] = __builtin_amdgcn_mfma_f32_16x16x32_bf16(
                    af1[rt], b1, acc[rt][ctl], 0, 0, 0);
            }
        }
    }

    // epilogue: +bias, cast, scatter to layout images
    #pragma unroll
    for (int ctl = 0; ctl < 3; ++ctl) {
        const int c    = (w * 3 + ctl) * 16 + lr;
        const int mmat = c >> 6;
        const int cc   = c & 63;
        const float* bp = (mmat == 0) ? bq : (mmat == 1) ? bk : bv;
        const float bias = bp[cc] * (mmat == 0 ? QSCALE : 1.0f);
        #pragma unroll
        for (int rt = 0; rt < 4; ++rt)
            #pragma unroll
            for (int r = 0; r < 4; ++r) {
                const int s = row0 + rt * 16 + lg * 4 + r;
                const ushort_t v = f2bf_fast(acc[rt][ctl][r] + bias);
                if (mmat == 0)
                    qimg[(size_t)s * 64 + cc] = v;
                else if (mmat == 1)
                    kimg[(size_t)(s >> 6) * 4096 + (s & 63) * 64 +
                         ((cc >> 3) ^ (s & 7)) * 8 + (cc & 7)] = v;
                else
                    vimg[(size_t)(s >> 6) * 4096 + (size_t)cc * 64 +
                         (((s & 63) >> 3) ^ (cc & 7)) * 8 + (s & 7)] = v;
            }
    }
}

// ---------------------------------------------------------------------------
// Kernel 2: causal flash attention, bf16 MFMA, S^T form, 2-way kv split-K.
// No-max softmax => partials are ADDITIVE: each half writes undivided O
// (fp32) + partial l to ws; merge kernel combines. Worst serial chain
// 64 -> 32 k-tile iters. Interleaved half dispatch = pairwise LPT.
// ---------------------------------------------------------------------------
__global__ __launch_bounds__(256) void attn(
    const ushort_t* __restrict__ qimg, const ushort_t* __restrict__ kimg,
    const ushort_t* __restrict__ vimg,
    float* __restrict__ Opart, float* __restrict__ Lpart)
{
    __shared__ ushort_t kvs[2][8192];   // slot: K img bytes 0..8191, V img 8192..16383
    __shared__ ushort_t ps[64][72];     // P[q][kv]; wave w owns rows 16w..16w+15

    const int t  = threadIdx.x;
    const int w  = t >> 6, l = t & 63, lr = l & 15, g = l >> 4;
    const int bx   = blockIdx.x;        // 1024 blocks
    const int half = bx & 1;
    const int u    = bx >> 1;
    const int qt   = 63 - (u >> 3);     // sizes descend pairwise -> LPT
    const int b    = u & 7;
    const int q0   = qt * 64;
    const int n    = qt + 1, h = n >> 1;
    const int t0   = half ? h : 0;
    const int t1   = half ? n : h;
    const int ch0 = (g ^ (lr & 7)) * 8;
    const int ch1 = ((g + 4) ^ (lr & 7)) * 8;
    const int qq  = q0 + w * 16 + lr;          // this lane's q-row (global)

    // Q as B-fragments (n = q = lr, k = d = g*8+j)
    bf16x8 qf0, qf1;
    {
        const ushort_t* qp = qimg + (size_t)(b * SEQ + qq) * 64 + g * 8;
        qf0 = *(const bf16x8*)(qp);
        qf1 = *(const bf16x8*)(qp + 32);
    }

    f32x4 o[4];
    #pragma unroll
    for (int dt = 0; dt < 4; ++dt) o[dt] = (f32x4){0.f,0.f,0.f,0.f};
    float lpart = 0.f;

    const char* kbase = (const char*)kimg + (size_t)b * 524288;
    const char* vbase = (const char*)vimg + (size_t)b * 524288;
    const int wo = w * 1024;
    const int lo = l * 16;

    if (t0 < t1) {      // prologue: stage tile t0 -> slot 0
        const char* ks = kbase + (size_t)t0 * 8192;
        const char* vs = vbase + (size_t)t0 * 8192;
        char* lk = (char*)&kvs[0][0];
        gld_lds16(ks + wo + lo,        lk + wo);
        gld_lds16(ks + wo + lo + 4096, lk + wo + 4096);
        gld_lds16(vs + wo + lo,        lk + wo + 8192);
        gld_lds16(vs + wo + lo + 4096, lk + wo + 12288);
    }

    for (int kt = t0; kt < t1; ++kt) {
        const int cur = (kt - t0) & 1;
        __syncthreads();                      // drains DMA for tile kt
        if (kt + 1 < t1) {                    // stage tile kt+1 into other slot
            const char* ks = kbase + (size_t)(kt + 1) * 8192;
            const char* vs = vbase + (size_t)(kt + 1) * 8192;
            char*       lk = (char*)&kvs[cur ^ 1][0];
            gld_lds16(ks + wo + lo,        lk + wo);
            gld_lds16(ks + wo + lo + 4096, lk + wo + 4096);
            gld_lds16(vs + wo + lo,        lk + wo + 8192);
            gld_lds16(vs + wo + lo + 4096, lk + wo + 12288);
        }

        // S^T = K . Q^T : A = K rows (m = kv), B = Q (n = q)
        const ushort_t* kb = &kvs[cur][0];
        f32x4 s[4];
        #pragma unroll
        for (int ct = 0; ct < 4; ++ct) {
            const int rowb = (ct * 16 + lr) * 64;
            bf16x8 kf0 = *(const bf16x8*)(kb + rowb + ch0);
            bf16x8 kf1 = *(const bf16x8*)(kb + rowb + ch1);
            s[ct] = (f32x4){0.f,0.f,0.f,0.f};
            s[ct] = __builtin_amdgcn_mfma_f32_16x16x32_bf16(kf0, qf0, s[ct], 0, 0, 0);
            s[ct] = __builtin_amdgcn_mfma_f32_16x16x32_bf16(kf1, qf1, s[ct], 0, 0, 0);
        }

        // exp2 + pack + P-write (lane's kv = kt*64 + ct*16 + g*4 + r, q = qq)
        if (kt == qt) {          // diagonal: causal mask (only in half 1)
            const int kvb = kt * 64 + g * 4;
            #pragma unroll
            for (int ct = 0; ct < 4; ++ct) {
                float p0 = ((kvb + ct*16 + 0) > qq) ? 0.f : __builtin_amdgcn_exp2f(s[ct][0]);
                float p1 = ((kvb + ct*16 + 1) > qq) ? 0.f : __builtin_amdgcn_exp2f(s[ct][1]);
                float p2 = ((kvb + ct*16 + 2) > qq) ? 0.f : __builtin_amdgcn_exp2f(s[ct][2]);
                float p3 = ((kvb + ct*16 + 3) > qq) ? 0.f : __builtin_amdgcn_exp2f(s[ct][3]);
                lpart += (p0 + p1) + (p2 + p3);
                u32x2 pk = { bfpair(p0, p1), bfpair(p2, p3) };
                *(u32x2*)&ps[w * 16 + lr][ct * 16 + g * 4] = pk;
            }
        } else {
            #pragma unroll
            for (int ct = 0; ct < 4; ++ct) {
                float p0 = __builtin_amdgcn_exp2f(s[ct][0]);
                float p1 = __builtin_amdgcn_exp2f(s[ct][1]);
                float p2 = __builtin_amdgcn_exp2f(s[ct][2]);
                float p3 = __builtin_amdgcn_exp2f(s[ct][3]);
                lpart += (p0 + p1) + (p2 + p3);
                u32x2 pk = { bfpair(p0, p1), bfpair(p2, p3) };
                *(u32x2*)&ps[w * 16 + lr][ct * 16 + g * 4] = pk;
            }
        }
        // cross-lane (within-wave) LDS dependence: drain DS queue
        asm volatile("s_waitcnt lgkmcnt(0)" ::: "memory");

        // O^T += V^T . P^T : A = V^T rows (m = d), B = P^T (n = q, k = kv)
        bf16x8 pf0 = *(const bf16x8*)&ps[w * 16 + lr][g * 8];
        bf16x8 pf1 = *(const bf16x8*)&ps[w * 16 + lr][32 + g * 8];
        const ushort_t* vb = &kvs[cur][4096];
        #pragma unroll
        for (int dt = 0; dt < 4; ++dt) {
            const int rowb = (dt * 16 + lr) * 64;
            bf16x8 vf0 = *(const bf16x8*)(vb + rowb + ch0);
            bf16x8 vf1 = *(const bf16x8*)(vb + rowb + ch1);
            o[dt] = __builtin_amdgcn_mfma_f32_16x16x32_bf16(vf0, pf0, o[dt], 0, 0, 0);
            o[dt] = __builtin_amdgcn_mfma_f32_16x16x32_bf16(vf1, pf1, o[dt], 0, 0, 0);
        }
    }

    // reduce l across the 4 quads (same q in lanes differing in bits 4,5)
    lpart += __shfl_xor(lpart, 16);
    lpart += __shfl_xor(lpart, 32);

    // store UNDIVIDED partial O (fp32) + partial l
    const int m = b * 64 + qt;
    float* Op = Opart + ((size_t)half * 512 + m) * 4096;
    #pragma unroll
    for (int dt = 0; dt < 4; ++dt)
        *(f32x4*)&Op[(w * 16 + lr) * 64 + dt * 16 + g * 4] = o[dt];
    if (g == 0)
        Lpart[((size_t)half * 512 + m) * 64 + w * 16 + lr] = lpart;
}

// ---------------------------------------------------------------------------
// Kernel 3: merge split-K halves: out = (Oa + Ob) / (la + lb)
// ---------------------------------------------------------------------------
__global__ __launch_bounds__(256) void merge_o(
    const float* __restrict__ Opart, const float* __restrict__ Lpart,
    float* __restrict__ outg)
{
    const int m = blockIdx.x;           // b*64 + qt
    const int b = m >> 6, qt = m & 63;
    const int t = threadIdx.x;
    const int row = t >> 2, c = (t & 3) * 16;

    const float* A = Opart + (size_t)m * 4096 + row * 64 + c;
    const float* B = Opart + (size_t)(512 + m) * 4096 + row * 64 + c;
    const float la = Lpart[(size_t)m * 64 + row];
    const float lb = Lpart[(size_t)(512 + m) * 64 + row];
    const float inv = 1.0f / (la + lb);
    float* dst = outg + ((size_t)b * SEQ + qt * 64 + row) * 64 + c;
    #pragma unroll
    for (int j = 0; j < 4; ++j) {
        float4 va = *(const float4*)(A + j * 4);
        float4 vb = *(const float4*)(B + j * 4);
        float4 vo = { (va.x + vb.x) * inv, (va.y + vb.y) * inv,
                      (va.z + vb.z) * inv, (va.w + vb.w) * inv };
        *(float4*)(dst + j * 4) = vo;
    }
}

extern "C" void kernel_launch(void* const* d_in, const int* in_sizes, int n_in,
                              void* d_out, int out_size, void* d_ws, size_t ws_size,
                              hipStream_t stream) {
    const float* x  = (const float*)d_in[0];
    const float* Wq = (const float*)d_in[1];
    const float* bq = (const float*)d_in[2];
    const float* Wk = (const float*)d_in[3];
    const float* bk = (const float*)d_in[4];
    const float* Wv = (const float*)d_in[5];
    const float* bv = (const float*)d_in[6];
    float* out = (float*)d_out;

    const size_t per = (size_t)NB * SEQ * DH;   // 2,097,152 bf16 elems = 4 MB
    ushort_t* q   = (ushort_t*)d_ws;
    ushort_t* k   = q + per;
    ushort_t* v   = k + per;
    ushort_t* wts = v + per;                    // 384 KB, ends at ~12.4 MB
    float* Opart  = (float*)((char*)d_ws + (size_t)(16u << 20));  // 16.8 MB
    float* Lpart  = (float*)((char*)d_ws + (size_t)(40u << 20));  // 256 KB

    prep_w  <<<dim3(48),   256, 0, stream>>>(Wq, Wk, Wv, wts);
    qkv_proj<<<dim3(512),  256, 0, stream>>>(x, wts, bq, bk, bv, q, k, v);
    attn    <<<dim3(1024), 256, 0, stream>>>(q, k, v, Opart, Lpart);
    merge_o <<<dim3(512),  256, 0, stream>>>(Opart, Lpart, out);
}

// Round 7
// 258.927 us; speedup vs baseline: 1.0560x; 1.0003x over previous
//
#include <hip/hip_runtime.h>
#include <hip/hip_bf16.h>
#include <math.h>

#define SEQ 4096
#define HID 1024
#define DH  64
#define NB  8
#define QSCALE 0.18033688011112042f   // 0.125 * log2(e): folds softmax scale + exp->exp2

typedef unsigned short ushort_t;
typedef unsigned int   uint_t;
typedef __attribute__((ext_vector_type(8))) short  bf16x8;
typedef __attribute__((ext_vector_type(4))) float  f32x4;
typedef __attribute__((ext_vector_type(4))) uint_t u32x4;
typedef __attribute__((ext_vector_type(2))) uint_t u32x2;

static __device__ __forceinline__ ushort_t f2bf(float f) {
    __hip_bfloat16 h = __float2bfloat16(f);   // RNE
    return *reinterpret_cast<ushort_t*>(&h);
}
// fast round-to-nearest bf16 (no NaN path; inputs finite)
static __device__ __forceinline__ ushort_t f2bf_fast(float f) {
    uint_t u = __float_as_uint(f);
    return (ushort_t)((u + 0x8000u) >> 16);
}
static __device__ __forceinline__ uint_t bfpair(float lo, float hi) {
    return (uint_t)f2bf_fast(lo) | ((uint_t)f2bf_fast(hi) << 16);
}

// async global->LDS DMA, 16 B per lane; lds dest = wave-uniform base + lane*16
static __device__ __forceinline__ void gld_lds16(const void* g, void* s) {
    __builtin_amdgcn_global_load_lds(
        (const __attribute__((address_space(1))) void*)g,
        (__attribute__((address_space(3))) void*)s, 16, 0, 0);
}

// ---------------------------------------------------------------------------
// Kernel 0: build wts = [Wq*QSCALE | Wk | Wv] transposed to [col][k], bf16,
// pre-swizzled per 64-k tile so proj can stage it as a flat DMA copy.
// ---------------------------------------------------------------------------
__global__ __launch_bounds__(256) void prep_w(
    const float* __restrict__ Wq, const float* __restrict__ Wk,
    const float* __restrict__ Wv, ushort_t* __restrict__ wts)
{
    __shared__ ushort_t tr[64][72];   // [k][c] bf16
    const int bx   = blockIdx.x;      // 48 = 3 mats x 16 k-tiles
    const int mmat = bx >> 4;
    const int kt   = bx & 15;
    const float* W  = (mmat == 0) ? Wq : (mmat == 1) ? Wk : Wv;
    const float  sc = (mmat == 0) ? QSCALE : 1.0f;

    const int t  = threadIdx.x;
    const int kr = t >> 2, kc = (t & 3) * 16;
    const float* src = W + (size_t)(kt * 64 + kr) * DH + kc;
    float4 a0 = *(const float4*)(src);
    float4 a1 = *(const float4*)(src + 4);
    float4 a2 = *(const float4*)(src + 8);
    float4 a3 = *(const float4*)(src + 12);
    float vv[16] = {a0.x,a0.y,a0.z,a0.w, a1.x,a1.y,a1.z,a1.w,
                    a2.x,a2.y,a2.z,a2.w, a3.x,a3.y,a3.z,a3.w};
    #pragma unroll
    for (int i = 0; i < 16; ++i) tr[kr][kc + i] = f2bf(vv[i] * sc);
    __syncthreads();

    const int cl = t >> 2, jc = (t & 3) * 16;
    const int c  = mmat * 64 + cl;
    ushort_t* dst = wts + kt * 12288 + c * 64;
    #pragma unroll
    for (int jj = 0; jj < 16; ++jj) {
        int j = jc + jj;
        dst[((j >> 3) ^ (cl & 7)) * 8 + (j & 7)] = tr[j][cl];
    }
}

// ---------------------------------------------------------------------------
// Kernel 1: fused QKV projection, bf16 MFMA.
// Wave owns 16 rows x ALL 192 cols: A-fragments load DIRECTLY from global x
// (k-contiguous 8-float chunks -> cvt in regs). No X LDS round-trip at all.
// W staged via double-buffered global_load_lds DMA; barrier only guards W.
// LDS = 48 KB -> 3 blocks/CU.
// ---------------------------------------------------------------------------
__global__ __launch_bounds__(256) void qkv_proj(
    const float* __restrict__ x, const ushort_t* __restrict__ wts,
    const float* __restrict__ bq, const float* __restrict__ bk,
    const float* __restrict__ bv,
    ushort_t* __restrict__ qimg, ushort_t* __restrict__ kimg,
    ushort_t* __restrict__ vimg)
{
    __shared__ ushort_t bw[2][12288];

    const int t  = threadIdx.x;
    const int w  = t >> 6, l = t & 63, lr = l & 15, g = l >> 4;
    const int row0 = blockIdx.x * 64;
    const int row  = row0 + w * 16 + lr;       // this lane's x-row (A m-index = lr)
    const int ch0 = (g ^ (lr & 7)) * 8;
    const int ch1 = ((g + 4) ^ (lr & 7)) * 8;

    f32x4 acc[12];
    #pragma unroll
    for (int i = 0; i < 12; ++i) acc[i] = (f32x4){0.f,0.f,0.f,0.f};

    const char* wbase = (const char*)wts;
    const int   wlo   = w * 1024 + l * 16;     // lane byte offset in 24 KB slice
    const float* xrow = x + (size_t)row * HID + g * 8;

    float4 Xa0, Xa1, Xb0, Xb1;                 // current tile: af0 <- Xa*, af1 <- Xb*
    {   // prologue: X tile 0 regs + DMA W tile 0 -> bw[0]
        Xa0 = *(const float4*)(xrow);
        Xa1 = *(const float4*)(xrow + 4);
        Xb0 = *(const float4*)(xrow + 32);
        Xb1 = *(const float4*)(xrow + 36);
        char* bdst = (char*)&bw[0][0] + w * 1024;
        #pragma unroll
        for (int i = 0; i < 6; ++i)
            gld_lds16(wbase + wlo + i * 4096, bdst + i * 4096);
    }

    for (int kt = 0; kt < 16; ++kt) {
        const int buf = kt & 1;
        __syncthreads();                       // drains bw[buf] DMA from last iter
        float4 Na0, Na1, Nb0, Nb1;
        if (kt < 15) {                         // prefetch tile kt+1
            const float* xn = xrow + (kt + 1) * 64;
            Na0 = *(const float4*)(xn);
            Na1 = *(const float4*)(xn + 4);
            Nb0 = *(const float4*)(xn + 32);
            Nb1 = *(const float4*)(xn + 36);
            char* bdst = (char*)&bw[buf ^ 1][0] + w * 1024;
            const char* bsrc = wbase + (size_t)(kt + 1) * 24576 + wlo;
            #pragma unroll
            for (int i = 0; i < 6; ++i)
                gld_lds16(bsrc + i * 4096, bdst + i * 4096);
        }
        // convert current X regs -> A fragments (k = g*8 + j)
        bf16x8 af0, af1;
        {
            u32x4 p;
            p.x = bfpair(Xa0.x, Xa0.y); p.y = bfpair(Xa0.z, Xa0.w);
            p.z = bfpair(Xa1.x, Xa1.y); p.w = bfpair(Xa1.z, Xa1.w);
            af0 = *(bf16x8*)&p;
            u32x4 q;
            q.x = bfpair(Xb0.x, Xb0.y); q.y = bfpair(Xb0.z, Xb0.w);
            q.z = bfpair(Xb1.x, Xb1.y); q.w = bfpair(Xb1.z, Xb1.w);
            af1 = *(bf16x8*)&q;
        }
        // 24 MFMAs over all 12 col-tiles
        #pragma unroll
        for (int ct = 0; ct < 12; ++ct) {
            const int c = ct * 16 + lr;
            bf16x8 b0 = *(bf16x8*)&bw[buf][c * 64 + ch0];
            bf16x8 b1 = *(bf16x8*)&bw[buf][c * 64 + ch1];
            acc[ct] = __builtin_amdgcn_mfma_f32_16x16x32_bf16(af0, b0, acc[ct], 0, 0, 0);
            acc[ct] = __builtin_amdgcn_mfma_f32_16x16x32_bf16(af1, b1, acc[ct], 0, 0, 0);
        }
        Xa0 = Na0; Xa1 = Na1; Xb0 = Nb0; Xb1 = Nb1;
    }

    // epilogue: +bias, cast, scatter to layout images.
    // C layout: lane (lr,g) holds D[row = w*16 + g*4 + r][col = ct*16 + lr]
    #pragma unroll
    for (int ct = 0; ct < 12; ++ct) {
        const int c    = ct * 16 + lr;
        const int mmat = c >> 6;
        const int cc   = c & 63;
        const float* bp = (mmat == 0) ? bq : (mmat == 1) ? bk : bv;
        const float bias = bp[cc] * (mmat == 0 ? QSCALE : 1.0f);
        #pragma unroll
        for (int r = 0; r < 4; ++r) {
            const int s = row0 + w * 16 + g * 4 + r;
            const ushort_t v = f2bf_fast(acc[ct][r] + bias);
            if (mmat == 0)
                qimg[(size_t)s * 64 + cc] = v;
            else if (mmat == 1)
                kimg[(size_t)(s >> 6) * 4096 + (s & 63) * 64 +
                     ((cc >> 3) ^ (s & 7)) * 8 + (cc & 7)] = v;
            else
                vimg[(size_t)(s >> 6) * 4096 + (size_t)cc * 64 +
                     (((s & 63) >> 3) ^ (cc & 7)) * 8 + (s & 7)] = v;
        }
    }
}

// ---------------------------------------------------------------------------
// Kernel 2: causal flash attention, bf16 MFMA, S^T form, 2-way kv split-K.
// No-max softmax => partials are ADDITIVE: each half writes undivided O
// (fp32) + partial l to ws; merge kernel combines.
// ---------------------------------------------------------------------------
__global__ __launch_bounds__(256) void attn(
    const ushort_t* __restrict__ qimg, const ushort_t* __restrict__ kimg,
    const ushort_t* __restrict__ vimg,
    float* __restrict__ Opart, float* __restrict__ Lpart)
{
    __shared__ ushort_t kvs[2][8192];   // slot: K img bytes 0..8191, V img 8192..16383
    __shared__ ushort_t ps[64][72];     // P[q][kv]; wave w owns rows 16w..16w+15

    const int t  = threadIdx.x;
    const int w  = t >> 6, l = t & 63, lr = l & 15, g = l >> 4;
    const int bx   = blockIdx.x;        // 1024 blocks
    const int half = bx & 1;
    const int u    = bx >> 1;
    const int qt   = 63 - (u >> 3);     // sizes descend pairwise -> LPT
    const int b    = u & 7;
    const int q0   = qt * 64;
    const int n    = qt + 1, h = n >> 1;
    const int t0   = half ? h : 0;
    const int t1   = half ? n : h;
    const int ch0 = (g ^ (lr & 7)) * 8;
    const int ch1 = ((g + 4) ^ (lr & 7)) * 8;
    const int qq  = q0 + w * 16 + lr;          // this lane's q-row (global)

    // Q as B-fragments (n = q = lr, k = d = g*8+j)
    bf16x8 qf0, qf1;
    {
        const ushort_t* qp = qimg + (size_t)(b * SEQ + qq) * 64 + g * 8;
        qf0 = *(const bf16x8*)(qp);
        qf1 = *(const bf16x8*)(qp + 32);
    }

    f32x4 o[4];
    #pragma unroll
    for (int dt = 0; dt < 4; ++dt) o[dt] = (f32x4){0.f,0.f,0.f,0.f};
    float lpart = 0.f;

    const char* kbase = (const char*)kimg + (size_t)b * 524288;
    const char* vbase = (const char*)vimg + (size_t)b * 524288;
    const int wo = w * 1024;
    const int lo = l * 16;

    if (t0 < t1) {      // prologue: stage tile t0 -> slot 0
        const char* ks = kbase + (size_t)t0 * 8192;
        const char* vs = vbase + (size_t)t0 * 8192;
        char* lk = (char*)&kvs[0][0];
        gld_lds16(ks + wo + lo,        lk + wo);
        gld_lds16(ks + wo + lo + 4096, lk + wo + 4096);
        gld_lds16(vs + wo + lo,        lk + wo + 8192);
        gld_lds16(vs + wo + lo + 4096, lk + wo + 12288);
    }

    for (int kt = t0; kt < t1; ++kt) {
        const int cur = (kt - t0) & 1;
        __syncthreads();                      // drains DMA for tile kt
        if (kt + 1 < t1) {                    // stage tile kt+1 into other slot
            const char* ks = kbase + (size_t)(kt + 1) * 8192;
            const char* vs = vbase + (size_t)(kt + 1) * 8192;
            char*       lk = (char*)&kvs[cur ^ 1][0];
            gld_lds16(ks + wo + lo,        lk + wo);
            gld_lds16(ks + wo + lo + 4096, lk + wo + 4096);
            gld_lds16(vs + wo + lo,        lk + wo + 8192);
            gld_lds16(vs + wo + lo + 4096, lk + wo + 12288);
        }

        // S^T = K . Q^T : A = K rows (m = kv), B = Q (n = q)
        const ushort_t* kb = &kvs[cur][0];
        f32x4 s[4];
        #pragma unroll
        for (int ct = 0; ct < 4; ++ct) {
            const int rowb = (ct * 16 + lr) * 64;
            bf16x8 kf0 = *(const bf16x8*)(kb + rowb + ch0);
            bf16x8 kf1 = *(const bf16x8*)(kb + rowb + ch1);
            s[ct] = (f32x4){0.f,0.f,0.f,0.f};
            s[ct] = __builtin_amdgcn_mfma_f32_16x16x32_bf16(kf0, qf0, s[ct], 0, 0, 0);
            s[ct] = __builtin_amdgcn_mfma_f32_16x16x32_bf16(kf1, qf1, s[ct], 0, 0, 0);
        }

        // exp2 + pack + P-write (lane's kv = kt*64 + ct*16 + g*4 + r, q = qq)
        if (kt == qt) {          // diagonal: causal mask (only in half 1)
            const int kvb = kt * 64 + g * 4;
            #pragma unroll
            for (int ct = 0; ct < 4; ++ct) {
                float p0 = ((kvb + ct*16 + 0) > qq) ? 0.f : __builtin_amdgcn_exp2f(s[ct][0]);
                float p1 = ((kvb + ct*16 + 1) > qq) ? 0.f : __builtin_amdgcn_exp2f(s[ct][1]);
                float p2 = ((kvb + ct*16 + 2) > qq) ? 0.f : __builtin_amdgcn_exp2f(s[ct][2]);
                float p3 = ((kvb + ct*16 + 3) > qq) ? 0.f : __builtin_amdgcn_exp2f(s[ct][3]);
                lpart += (p0 + p1) + (p2 + p3);
                u32x2 pk = { bfpair(p0, p1), bfpair(p2, p3) };
                *(u32x2*)&ps[w * 16 + lr][ct * 16 + g * 4] = pk;
            }
        } else {
            #pragma unroll
            for (int ct = 0; ct < 4; ++ct) {
                float p0 = __builtin_amdgcn_exp2f(s[ct][0]);
                float p1 = __builtin_amdgcn_exp2f(s[ct][1]);
                float p2 = __builtin_amdgcn_exp2f(s[ct][2]);
                float p3 = __builtin_amdgcn_exp2f(s[ct][3]);
                lpart += (p0 + p1) + (p2 + p3);
                u32x2 pk = { bfpair(p0, p1), bfpair(p2, p3) };
                *(u32x2*)&ps[w * 16 + lr][ct * 16 + g * 4] = pk;
            }
        }
        // cross-lane (within-wave) LDS dependence: drain DS queue
        asm volatile("s_waitcnt lgkmcnt(0)" ::: "memory");

        // O^T += V^T . P^T : A = V^T rows (m = d), B = P^T (n = q, k = kv)
        bf16x8 pf0 = *(const bf16x8*)&ps[w * 16 + lr][g * 8];
        bf16x8 pf1 = *(const bf16x8*)&ps[w * 16 + lr][32 + g * 8];
        const ushort_t* vb = &kvs[cur][4096];
        #pragma unroll
        for (int dt = 0; dt < 4; ++dt) {
            const int rowb = (dt * 16 + lr) * 64;
            bf16x8 vf0 = *(const bf16x8*)(vb + rowb + ch0);
            bf16x8 vf1 = *(const bf16x8*)(vb + rowb + ch1);
            o[dt] = __builtin_amdgcn_mfma_f32_16x16x32_bf16(vf0, pf0, o[dt], 0, 0, 0);
            o[dt] = __builtin_amdgcn_mfma_f32_16x16x32_bf16(vf1, pf1, o[dt], 0, 0, 0);
        }
    }

    // reduce l across the 4 quads (same q in lanes differing in bits 4,5)
    lpart += __shfl_xor(lpart, 16);
    lpart += __shfl_xor(lpart, 32);

    // store UNDIVIDED partial O (fp32) + partial l
    const int m = b * 64 + qt;
    float* Op = Opart + ((size_t)half * 512 + m) * 4096;
    #pragma unroll
    for (int dt = 0; dt < 4; ++dt)
        *(f32x4*)&Op[(w * 16 + lr) * 64 + dt * 16 + g * 4] = o[dt];
    if (g == 0)
        Lpart[((size_t)half * 512 + m) * 64 + w * 16 + lr] = lpart;
}

// ---------------------------------------------------------------------------
// Kernel 3: merge split-K halves: out = (Oa + Ob) / (la + lb)
// ---------------------------------------------------------------------------
__global__ __launch_bounds__(256) void merge_o(
    const float* __restrict__ Opart, const float* __restrict__ Lpart,
    float* __restrict__ outg)
{
    const int m = blockIdx.x;           // b*64 + qt
    const int b = m >> 6, qt = m & 63;
    const int t = threadIdx.x;
    const int row = t >> 2, c = (t & 3) * 16;

    const float* A = Opart + (size_t)m * 4096 + row * 64 + c;
    const float* B = Opart + (size_t)(512 + m) * 4096 + row * 64 + c;
    const float la = Lpart[(size_t)m * 64 + row];
    const float lb = Lpart[(size_t)(512 + m) * 64 + row];
    const float inv = 1.0f / (la + lb);
    float* dst = outg + ((size_t)b * SEQ + qt * 64 + row) * 64 + c;
    #pragma unroll
    for (int j = 0; j < 4; ++j) {
        float4 va = *(const float4*)(A + j * 4);
        float4 vb = *(const float4*)(B + j * 4);
        float4 vo = { (va.x + vb.x) * inv, (va.y + vb.y) * inv,
                      (va.z + vb.z) * inv, (va.w + vb.w) * inv };
        *(float4*)(dst + j * 4) = vo;
    }
}

extern "C" void kernel_launch(void* const* d_in, const int* in_sizes, int n_in,
                              void* d_out, int out_size, void* d_ws, size_t ws_size,
                              hipStream_t stream) {
    const float* x  = (const float*)d_in[0];
    const float* Wq = (const float*)d_in[1];
    const float* bq = (const float*)d_in[2];
    const float* Wk = (const float*)d_in[3];
    const float* bk = (const float*)d_in[4];
    const float* Wv = (const float*)d_in[5];
    const float* bv = (const float*)d_in[6];
    float* out = (float*)d_out;

    const size_t per = (size_t)NB * SEQ * DH;   // 2,097,152 bf16 elems = 4 MB
    ushort_t* q   = (ushort_t*)d_ws;
    ushort_t* k   = q + per;
    ushort_t* v   = k + per;
    ushort_t* wts = v + per;                    // 384 KB
    float* Opart  = (float*)((char*)d_ws + (size_t)(16u << 20));  // 16.8 MB
    float* Lpart  = (float*)((char*)d_ws + (size_t)(40u << 20));  // 256 KB

    prep_w  <<<dim3(48),   256, 0, stream>>>(Wq, Wk, Wv, wts);
    qkv_proj<<<dim3(512),  256, 0, stream>>>(x, wts, bq, bk, bv, q, k, v);
    attn    <<<dim3(1024), 256, 0, stream>>>(q, k, v, Opart, Lpart);
    merge_o <<<dim3(512),  256, 0, stream>>>(Opart, Lpart, out);
}